// Round 6
// baseline (876.802 us; speedup 1.0000x reference)
//
#include <hip/hip_runtime.h>

#define BQ 4
#define CQ 512
#define TQ 1024
#define FQ 2048
#define LQ 4
#define HQ 8
#define MT (BQ * TQ)            // batch-folded rows = 4096

typedef __attribute__((ext_vector_type(8))) short short8;
typedef __attribute__((ext_vector_type(4))) float floatx4;

#define MFMA16(a, b, c) __builtin_amdgcn_mfma_f32_16x16x32_bf16(a, b, c, 0, 0, 0)

static __device__ __forceinline__ unsigned short f2bf(float f) {
  union { float f; unsigned u; } v; v.f = f;
  unsigned r = v.u + 0x7fff + ((v.u >> 16) & 1);
  return (unsigned short)(r >> 16);
}

static __device__ __forceinline__ void async_copy16(const void* g, void* l) {
  __builtin_amdgcn_global_load_lds(
      (const __attribute__((address_space(1))) void*)g,
      (__attribute__((address_space(3))) void*)l, 16, 0, 0);
}

// ---------------------------------------------------------------------------
// bf16 MFMA GEMM: Y[m,n] = epi( sum_k A[m, ko+k] B[n, ko+k] ), ko = z*kofs
// 128x128 tile, BK=32, 4 waves (2x2). flags: 1=relu 2=premask(row m)
// 4=postmask(row m) 16=bf16 out 32=raw fp32 (split-K partial, Y += z*sYb)
// ---------------------------------------------------------------------------
__global__ __launch_bounds__(256) void mfma_gemm(
    const unsigned short* __restrict__ A, const unsigned short* __restrict__ B,
    void* __restrict__ Y, const float* __restrict__ bias,
    const float* __restrict__ mask, int M, int N, int K, int lda, int ldb,
    long long kofs, long long sYb, float scale, int flags)
{
  const int tid = threadIdx.x;
  const int w = tid >> 6, lane = tid & 63;
  const int wm = w >> 1, wn = w & 1;
  const int m0 = blockIdx.y * 128, n0 = blockIdx.x * 128;
  const size_t ko = (size_t)blockIdx.z * kofs;

  __shared__ unsigned short sA[128 * 32];
  __shared__ unsigned short sB[128 * 32];

  floatx4 acc[4][4];
#pragma unroll
  for (int i = 0; i < 4; i++)
#pragma unroll
    for (int j = 0; j < 4; j++) acc[i][j] = floatx4{0.f, 0.f, 0.f, 0.f};

  const int srow = lane >> 2;
  const int skel = (lane & 3) * 8;
  const int col = lane & 15, gq = lane >> 4;

  for (int k0 = 0; k0 < K; k0 += 32) {
#pragma unroll
    for (int r = 0; r < 2; r++) {
      int c = r * 4 + w;
      async_copy16(&A[(size_t)(m0 + c * 16 + srow) * lda + ko + k0 + skel],
                   &sA[c * 512]);
      async_copy16(&B[(size_t)(n0 + c * 16 + srow) * ldb + ko + k0 + skel],
                   &sB[c * 512]);
    }
    __syncthreads();

    short8 af[4], bfr[4];
#pragma unroll
    for (int im = 0; im < 4; im++)
      af[im] = *(const short8*)&sA[(wm * 64 + im * 16 + col) * 32 + gq * 8];
#pragma unroll
    for (int in = 0; in < 4; in++)
      bfr[in] = *(const short8*)&sB[(wn * 64 + in * 16 + col) * 32 + gq * 8];
#pragma unroll
    for (int im = 0; im < 4; im++)
#pragma unroll
      for (int in = 0; in < 4; in++)
        acc[im][in] = MFMA16(af[im], bfr[in], acc[im][in]);
    __syncthreads();
  }

  const bool relu  = flags & 1;
  const bool prem  = flags & 2;
  const bool postm = flags & 4;
  const bool bf16o = flags & 16;
  const bool raw   = flags & 32;
  float* Yf = (float*)Y + (size_t)blockIdx.z * sYb;
  unsigned short* Yh = (unsigned short*)Y;

#pragma unroll
  for (int im = 0; im < 4; im++)
#pragma unroll
    for (int in = 0; in < 4; in++) {
      int nn = n0 + wn * 64 + in * 16 + col;
      float bn = raw ? 0.f : bias[nn];
#pragma unroll
      for (int reg = 0; reg < 4; reg++) {
        int mm = m0 + wm * 64 + im * 16 + gq * 4 + reg;
        float val = acc[im][in][reg];
        if (raw) {
          Yf[(size_t)mm * N + nn] = val;
        } else {
          float mv = (prem || postm) ? mask[mm] : 1.f;
          if (prem) val *= mv;
          val = (val + bn) * scale;
          if (relu) val = fmaxf(val, 0.f);
          if (postm) val *= mv;
          if (bf16o) Yh[(size_t)mm * N + nn] = f2bf(val);
          else       Yf[(size_t)mm * N + nn] = val;
        }
      }
    }
}

// ---------------------------------------------------------------------------
// Fused QKV GEMM: A = x bf16 (MT x 512), B = [wq;wk;wv] bf16 (1536 x 512).
// n-tile never crosses a 512 boundary -> uniform segment per block.
// Q gets scale 0.125. Outputs bf16 (B,T,C) each.
// ---------------------------------------------------------------------------
__global__ __launch_bounds__(256) void qkv_gemm(
    const unsigned short* __restrict__ A, const unsigned short* __restrict__ B,
    unsigned short* __restrict__ qo, unsigned short* __restrict__ ko2,
    unsigned short* __restrict__ vo, const float* __restrict__ qb,
    const float* __restrict__ kb, const float* __restrict__ vb)
{
  const int tid = threadIdx.x;
  const int w = tid >> 6, lane = tid & 63;
  const int wm = w >> 1, wn = w & 1;
  const int m0 = blockIdx.y * 128, n0 = blockIdx.x * 128;

  __shared__ unsigned short sA[128 * 32];
  __shared__ unsigned short sB[128 * 32];

  floatx4 acc[4][4];
#pragma unroll
  for (int i = 0; i < 4; i++)
#pragma unroll
    for (int j = 0; j < 4; j++) acc[i][j] = floatx4{0.f, 0.f, 0.f, 0.f};

  const int srow = lane >> 2;
  const int skel = (lane & 3) * 8;
  const int col = lane & 15, gq = lane >> 4;

  for (int k0 = 0; k0 < CQ; k0 += 32) {
#pragma unroll
    for (int r = 0; r < 2; r++) {
      int c = r * 4 + w;
      async_copy16(&A[(size_t)(m0 + c * 16 + srow) * CQ + k0 + skel],
                   &sA[c * 512]);
      async_copy16(&B[(size_t)(n0 + c * 16 + srow) * CQ + k0 + skel],
                   &sB[c * 512]);
    }
    __syncthreads();

    short8 af[4], bfr[4];
#pragma unroll
    for (int im = 0; im < 4; im++)
      af[im] = *(const short8*)&sA[(wm * 64 + im * 16 + col) * 32 + gq * 8];
#pragma unroll
    for (int in = 0; in < 4; in++)
      bfr[in] = *(const short8*)&sB[(wn * 64 + in * 16 + col) * 32 + gq * 8];
#pragma unroll
    for (int im = 0; im < 4; im++)
#pragma unroll
      for (int in = 0; in < 4; in++)
        acc[im][in] = MFMA16(af[im], bfr[in], acc[im][in]);
    __syncthreads();
  }

  const int seg = n0 >> 9;
  unsigned short* Yh = (seg == 0) ? qo : (seg == 1) ? ko2 : vo;
  const float* bp = (seg == 0) ? qb : (seg == 1) ? kb : vb;
  const float scale = (seg == 0) ? 0.125f : 1.f;
  const int nbase = n0 - seg * 512;

#pragma unroll
  for (int im = 0; im < 4; im++)
#pragma unroll
    for (int in = 0; in < 4; in++) {
      int nn = nbase + wn * 64 + in * 16 + col;
      float bn = bp[nn];
#pragma unroll
      for (int reg = 0; reg < 4; reg++) {
        int mm = m0 + wm * 64 + im * 16 + gq * 4 + reg;
        Yh[(size_t)mm * CQ + nn] = f2bf((acc[im][in][reg] + bn) * scale);
      }
    }
}

// ---------------------------------------------------------------------------
// MFMA flash attention, j-split across waves (fixed-origin softmax allows
// trivial partial-sum merge). Block = 16 Q rows; wave w owns j-tiles
// [w*4, w*4+4) of 64 j each. Merge O/l partials through LDS at the end.
// q,k bf16 (B,T,C); v bf16 (B,C,T); o bf16 (B,T,C).
// ---------------------------------------------------------------------------
__global__ __launch_bounds__(256) void attn_kernel(
    const unsigned short* __restrict__ qt, const unsigned short* __restrict__ kt,
    const unsigned short* __restrict__ vt, const float* __restrict__ mask,
    const float* __restrict__ rk, const float* __restrict__ rv,
    unsigned short* __restrict__ o)
{
  const int b = blockIdx.z, h = blockIdx.y;
  const int w = threadIdx.x >> 6;
  const int lane = threadIdx.x & 63;
  const int col = lane & 15, g = lane >> 4;
  const int i0 = blockIdx.x * 16;

  const unsigned short* qb = qt + (size_t)b * TQ * CQ + h * 64;
  const unsigned short* kb = kt + (size_t)b * TQ * CQ + h * 64;
  const unsigned short* vb = vt + ((size_t)b * CQ + h * 64) * TQ;
  unsigned short* ob = o + (size_t)b * TQ * CQ + h * 64;

  __shared__ unsigned short pbuf[4][16][72];
  __shared__ float rkdl[4][16][9];
  __shared__ float pband[16][9];       // block-shared; disjoint writes
  __shared__ float opart[4][16][68];
  __shared__ float lpart[4][16];

  short8 qf0 = *(const short8*)&qb[(size_t)(i0 + col) * CQ + g * 8];
  short8 qf1 = *(const short8*)&qb[(size_t)(i0 + col) * CQ + 32 + g * 8];

  // rkd[i][delta] = q_i . rk_delta via MFMA (wave-private copy)
  {
    short8 rb0 = {0, 0, 0, 0, 0, 0, 0, 0}, rb1 = rb0;
    if (col < 9) {
#pragma unroll
      for (int i = 0; i < 8; i++) {
        rb0[i] = (short)f2bf(rk[col * 64 + g * 8 + i]);
        rb1[i] = (short)f2bf(rk[col * 64 + 32 + g * 8 + i]);
      }
    }
    floatx4 rc = {0.f, 0.f, 0.f, 0.f};
    rc = MFMA16(qf0, rb0, rc);
    rc = MFMA16(qf1, rb1, rc);
    if (col < 9) {
#pragma unroll
      for (int reg = 0; reg < 4; reg++) rkdl[w][g * 4 + reg][col] = rc[reg];
    }
  }
  for (int e = threadIdx.x; e < 144; e += 256) pband[e / 9][e % 9] = 0.f;
  __syncthreads();  // pband zero + rkdl visible

  float l_lane[4] = {0.f, 0.f, 0.f, 0.f};
  floatx4 oacc[4];
#pragma unroll
  for (int r = 0; r < 4; r++) oacc[r] = floatx4{0.f, 0.f, 0.f, 0.f};

#pragma unroll
  for (int t = 0; t < 4; t++) {
    const int j0 = (w * 4 + t) * 64;
    // ---- S = Q K^T ----
    floatx4 sc[4];
#pragma unroll
    for (int jg = 0; jg < 4; jg++) {
      const size_t kr = (size_t)(j0 + jg * 16 + col) * CQ;
      short8 kf0 = *(const short8*)&kb[kr + g * 8];
      short8 kf1 = *(const short8*)&kb[kr + 32 + g * 8];
      floatx4 z = {0.f, 0.f, 0.f, 0.f};
      z = MFMA16(qf0, kf0, z);
      sc[jg] = MFMA16(qf1, kf1, z);
    }
    float mv[4];
#pragma unroll
    for (int jg = 0; jg < 4; jg++)
      mv[jg] = mask[(size_t)b * TQ + j0 + jg * 16 + col];

    const bool inband = (j0 <= i0 + 19) && (j0 + 63 >= i0 - 4);

    float p[4][4];
#pragma unroll
    for (int reg = 0; reg < 4; reg++) {
      const int ig = i0 + g * 4 + reg;
#pragma unroll
      for (int jg = 0; jg < 4; jg++) {
        float s = sc[jg][reg];
        if (inband) {
          int dlt = j0 + jg * 16 + col - ig + 4;
          if (dlt >= 0 && dlt < 9) s += rkdl[w][g * 4 + reg][dlt];
        }
        float pv = (mv[jg] == 0.f) ? 0.f : __expf(s);
        p[reg][jg] = pv;
        l_lane[reg] += pv;
      }
    }

    if (inband) {
#pragma unroll
      for (int reg = 0; reg < 4; reg++) {
        const int row = g * 4 + reg;
#pragma unroll
        for (int jg = 0; jg < 4; jg++) {
          int dlt = j0 + jg * 16 + col - (i0 + row) + 4;
          if (dlt >= 0 && dlt < 9) pband[row][dlt] = p[reg][jg];
        }
      }
    }

    // ---- P -> LDS (C-layout) -> A-layout fragments ----
#pragma unroll
    for (int reg = 0; reg < 4; reg++)
#pragma unroll
      for (int jg = 0; jg < 4; jg++)
        pbuf[w][g * 4 + reg][jg * 16 + col] = f2bf(p[reg][jg]);
    __builtin_amdgcn_wave_barrier();
    short8 pf0 = *(const short8*)&pbuf[w][col][g * 8];
    short8 pf1 = *(const short8*)&pbuf[w][col][32 + g * 8];

    // ---- O += P V ----
#pragma unroll
    for (int dg = 0; dg < 4; dg++) {
      const size_t vr = (size_t)(dg * 16 + col) * TQ + j0;
      short8 vf0 = *(const short8*)&vb[vr + g * 8];
      short8 vf1 = *(const short8*)&vb[vr + 32 + g * 8];
      oacc[dg] = MFMA16(pf0, vf0, oacc[dg]);
      oacc[dg] = MFMA16(pf1, vf1, oacc[dg]);
    }
    __builtin_amdgcn_wave_barrier();
  }

  // ---- merge partials across waves ----
#pragma unroll
  for (int reg = 0; reg < 4; reg++) {
    float l = l_lane[reg];
#pragma unroll
    for (int off = 1; off < 16; off <<= 1) l += __shfl_xor(l, off, 64);
    if (col == 0) lpart[w][g * 4 + reg] = l;
  }
#pragma unroll
  for (int dg = 0; dg < 4; dg++)
#pragma unroll
    for (int reg = 0; reg < 4; reg++)
      opart[w][g * 4 + reg][dg * 16 + col] = oacc[dg][reg];
  __syncthreads();

  if (w == 0) {
    float inv_l[4];
#pragma unroll
    for (int reg = 0; reg < 4; reg++) {
      int row = g * 4 + reg;
      inv_l[reg] = 1.f / (lpart[0][row] + lpart[1][row] +
                          lpart[2][row] + lpart[3][row]);
    }
#pragma unroll
    for (int dg = 0; dg < 4; dg++) {
      const int d = dg * 16 + col;
      float rvd[9];
#pragma unroll
      for (int dlt = 0; dlt < 9; dlt++) rvd[dlt] = rv[dlt * 64 + d];
#pragma unroll
      for (int reg = 0; reg < 4; reg++) {
        const int row = g * 4 + reg;
        float val = opart[0][row][d] + opart[1][row][d] +
                    opart[2][row][d] + opart[3][row][d];
        float rvc = 0.f;
#pragma unroll
        for (int dlt = 0; dlt < 9; dlt++) rvc += pband[row][dlt] * rvd[dlt];
        ob[(size_t)(i0 + row) * CQ + d] = f2bf((val + rvc) * inv_l[reg]);
      }
    }
  }
}

// ---------------------------------------------------------------------------
// Residual + LayerNorm rows (C=512 contiguous). v = res + s*(a1+a2+addb[c]),
// s = mask if (mode&1). y = LN(v)*g+b; if (mode&2) y *= mask.
// ---------------------------------------------------------------------------
__global__ __launch_bounds__(256) void ln_rows(
    const float* __restrict__ res, const float* __restrict__ a1,
    const float* __restrict__ a2, const float* __restrict__ addb,
    const float* __restrict__ g, const float* __restrict__ bb,
    const float* __restrict__ mask, float* __restrict__ outf,
    unsigned short* __restrict__ outb, int mode)
{
  const int row = blockIdx.x * 4 + (threadIdx.x >> 6);
  const int lane = threadIdx.x & 63;
  const size_t base = (size_t)row * CQ + lane * 8;
  const int c0 = lane * 8;

  float mv = mask[row];
  float sadd = (mode & 1) ? mv : 1.f;

  float v[8];
#pragma unroll
  for (int i = 0; i < 8; i += 4) {
    float4 r = *(const float4*)&res[base + i];
    float4 x1 = *(const float4*)&a1[base + i];
    float4 x2 = *(const float4*)&a2[base + i];
    float4 bv = *(const float4*)&addb[c0 + i];
    v[i + 0] = r.x + sadd * (x1.x + x2.x + bv.x);
    v[i + 1] = r.y + sadd * (x1.y + x2.y + bv.y);
    v[i + 2] = r.z + sadd * (x1.z + x2.z + bv.z);
    v[i + 3] = r.w + sadd * (x1.w + x2.w + bv.w);
  }
  float sum = 0.f, ssq = 0.f;
#pragma unroll
  for (int i = 0; i < 8; i++) { sum += v[i]; ssq += v[i] * v[i]; }
#pragma unroll
  for (int off = 1; off < 64; off <<= 1) {
    sum += __shfl_xor(sum, off, 64);
    ssq += __shfl_xor(ssq, off, 64);
  }
  float mean = sum * (1.f / CQ);
  float var = ssq * (1.f / CQ) - mean * mean;
  float rstd = rsqrtf(var + 1e-6f);
  float pm = (mode & 2) ? mv : 1.f;

  float y[8];
#pragma unroll
  for (int i = 0; i < 8; i++)
    y[i] = ((v[i] - mean) * rstd * g[c0 + i] + bb[c0 + i]) * pm;
  float4 o0 = {y[0], y[1], y[2], y[3]}, o1 = {y[4], y[5], y[6], y[7]};
  *(float4*)&outf[base] = o0;
  *(float4*)&outf[base + 4] = o1;
  if (outb) {
    ushort4 u0 = {f2bf(y[0]), f2bf(y[1]), f2bf(y[2]), f2bf(y[3])};
    ushort4 u1 = {f2bf(y[4]), f2bf(y[5]), f2bf(y[6]), f2bf(y[7])};
    *(ushort4*)&outb[base] = u0;
    *(ushort4*)&outb[base + 4] = u1;
  }
}

// ---------------------------------------------------------------------------
// Transpose-in: x (B,C,T) fp32 -> xa fp32 (B,T,C) + xab bf16 (B,T,C)
// ---------------------------------------------------------------------------
__global__ __launch_bounds__(256) void tr_in(
    const float* __restrict__ x, float* __restrict__ xa,
    unsigned short* __restrict__ xab)
{
  __shared__ float s[32][33];
  const int b = blockIdx.z, t0 = blockIdx.x * 32, c0 = blockIdx.y * 32;
  const int tx = threadIdx.x, ty = threadIdx.y;
#pragma unroll
  for (int r = 0; r < 4; r++)
    s[ty + r * 8][tx] = x[((size_t)b * CQ + c0 + ty + r * 8) * TQ + t0 + tx];
  __syncthreads();
#pragma unroll
  for (int r = 0; r < 4; r++) {
    float v = s[tx][ty + r * 8];
    size_t idx = ((size_t)b * TQ + t0 + ty + r * 8) * CQ + c0 + tx;
    xa[idx] = v;
    xab[idx] = f2bf(v);
  }
}

// ---------------------------------------------------------------------------
// Transpose-out: y (B,T,C) fp32 -> out (B,C,T) fp32
// ---------------------------------------------------------------------------
__global__ __launch_bounds__(256) void tr_out(
    const float* __restrict__ y, float* __restrict__ out)
{
  __shared__ float s[32][33];
  const int b = blockIdx.z, t0 = blockIdx.x * 32, c0 = blockIdx.y * 32;
  const int tx = threadIdx.x, ty = threadIdx.y;
#pragma unroll
  for (int r = 0; r < 4; r++)
    s[ty + r * 8][tx] = y[((size_t)b * TQ + t0 + ty + r * 8) * CQ + c0 + tx];
  __syncthreads();
#pragma unroll
  for (int r = 0; r < 4; r++)
    out[((size_t)b * CQ + c0 + ty + r * 8) * TQ + t0 + tx] = s[tx][ty + r * 8];
}

// ---------------------------------------------------------------------------
// V transpose: bf16 (B,T,C) -> bf16 (B,C,T)
// ---------------------------------------------------------------------------
__global__ __launch_bounds__(256) void vtr(
    const unsigned short* __restrict__ in, unsigned short* __restrict__ out)
{
  __shared__ unsigned short s[32][33];
  const int b = blockIdx.z, t0 = blockIdx.x * 32, c0 = blockIdx.y * 32;
  const int tx = threadIdx.x, ty = threadIdx.y;
#pragma unroll
  for (int r = 0; r < 4; r++)
    s[ty + r * 8][tx] = in[((size_t)b * TQ + t0 + ty + r * 8) * CQ + c0 + tx];
  __syncthreads();
#pragma unroll
  for (int r = 0; r < 4; r++)
    out[((size_t)b * CQ + c0 + ty + r * 8) * TQ + t0 + tx] = s[tx][ty + r * 8];
}

// ---------------------------------------------------------------------------
// Per-layer weight fp32 -> bf16 (layouts contiguous: fused QKV = rows 0..1535)
// ---------------------------------------------------------------------------
__global__ __launch_bounds__(256) void wconv(
    const float* __restrict__ qw, const float* __restrict__ kw,
    const float* __restrict__ vw, const float* __restrict__ ow,
    const float* __restrict__ w1, const float* __restrict__ w2,
    unsigned short* __restrict__ dst)
{
  int idx4 = blockIdx.x * 256 + threadIdx.x;
  int i = idx4 * 4;
  const float* src;
  int off;
  if (i < 1048576) {
    int which = i >> 18;
    src = (which == 0) ? qw : (which == 1) ? kw : (which == 2) ? vw : ow;
    off = i & 262143;
  } else if (i < 2097152) {
    src = w1; off = i - 1048576;
  } else {
    src = w2; off = i - 2097152;
  }
  float4 v = *(const float4*)&src[off];
  ushort4 u = {f2bf(v.x), f2bf(v.y), f2bf(v.z), f2bf(v.w)};
  *(ushort4*)&dst[i] = u;
}

// ---------------------------------------------------------------------------
extern "C" void kernel_launch(void* const* d_in, const int* in_sizes, int n_in,
                              void* d_out, int out_size, void* d_ws, size_t ws_size,
                              hipStream_t stream) {
  const float* x    = (const float*)d_in[0];
  const float* mask = (const float*)d_in[1];
  const float* qw   = (const float*)d_in[2];
  const float* qbb  = (const float*)d_in[3];
  const float* kw   = (const float*)d_in[4];
  const float* kbb  = (const float*)d_in[5];
  const float* vw   = (const float*)d_in[6];
  const float* vbb  = (const float*)d_in[7];
  const float* ow   = (const float*)d_in[8];
  const float* obb  = (const float*)d_in[9];
  const float* rk   = (const float*)d_in[10];
  const float* rv   = (const float*)d_in[11];
  const float* g1   = (const float*)d_in[12];
  const float* be1  = (const float*)d_in[13];
  const float* w1   = (const float*)d_in[14];
  const float* b1   = (const float*)d_in[15];
  const float* w2   = (const float*)d_in[16];
  const float* b2   = (const float*)d_in[17];
  const float* g2   = (const float*)d_in[18];
  const float* be2  = (const float*)d_in[19];
  float* out = (float*)d_out;

  const size_t MB = 1 << 20;
  char* base = (char*)d_ws;
  unsigned short* wbuf  = (unsigned short*)(base);            // 6 MB
  float*          xa    = (float*)(base + 6 * MB);            // 8 MB fp32 (B,T,C)
  unsigned short* xab   = (unsigned short*)(base + 14 * MB);  // 4 MB bf16 (B,T,C)
  unsigned short* qtb   = (unsigned short*)(base + 18 * MB);  // 4 MB
  unsigned short* ktb   = (unsigned short*)(base + 22 * MB);  // 4 MB
  unsigned short* vtmp  = (unsigned short*)(base + 26 * MB);  // 4 MB (B,T,C)
  unsigned short* vtb   = (unsigned short*)(base + 30 * MB);  // 4 MB (B,C,T)
  unsigned short* obufb = (unsigned short*)(base + 34 * MB);  // 4 MB (B,T,C)
  float*          t1    = (float*)(base + 38 * MB);           // 8 MB fp32
  // t1b = t1 + MT*CQ (contiguous @46 MB, 8 MB) -- split-K partial 2
  unsigned short* hbuf  = qtb;   // FFN hidden bf16 (B,T,F): 16 MB over 18..34

  const unsigned short* wo  = wbuf + 786432;
  const unsigned short* wf1 = wbuf + 1048576;
  const unsigned short* wf2 = wbuf + 2097152;
  const long long sY = (long long)MT * CQ;
  float* t1b = t1 + sY;

  dim3 b256(256);
  dim3 gtr(TQ / 32, CQ / 32, BQ);
  dim3 gln(MT / 4);

  hipLaunchKernelGGL(tr_in, gtr, dim3(32, 8), 0, stream, x, xa, xab);

  for (int i = 0; i < LQ; i++) {
    hipLaunchKernelGGL(wconv, dim3(3072), b256, 0, stream,
        qw + (size_t)i * CQ * CQ, kw + (size_t)i * CQ * CQ,
        vw + (size_t)i * CQ * CQ, ow + (size_t)i * CQ * CQ,
        w1 + (size_t)i * FQ * CQ, w2 + (size_t)i * CQ * FQ, wbuf);
    // fused QKV: (4096 x 1536) <- x(4096x512) . W^T, 384 blocks
    hipLaunchKernelGGL(qkv_gemm, dim3(12, 32), b256, 0, stream,
        xab, wbuf, qtb, ktb, vtmp, qbb + i * CQ, kbb + i * CQ, vbb + i * CQ);
    hipLaunchKernelGGL(vtr, gtr, dim3(32, 8), 0, stream, vtmp, vtb);
    // attention: 16 Q rows per block, 4 waves split the j range
    hipLaunchKernelGGL(attn_kernel, dim3(TQ / 16, HQ, BQ), b256, 0, stream,
        qtb, ktb, vtb, mask, rk + (size_t)i * 576, rv + (size_t)i * 576, obufb);
    // o-proj split-K=2 raw partials -> t1, t1b (256 blocks)
    hipLaunchKernelGGL(mfma_gemm, dim3(4, 32, 2), b256, 0, stream,
        obufb, wo, (void*)t1, (const float*)0, mask,
        MT, CQ, CQ / 2, CQ, CQ, (long long)(CQ / 2), sY, 1.f, 32);
    hipLaunchKernelGGL(ln_rows, gln, b256, 0, stream,
        xa, t1, t1b, obb + i * CQ, g1 + i * CQ, be1 + i * CQ, mask,
        xa, xab, 0);
    // FFN1 (512 blocks): premask+relu+postmask, bf16 out
    hipLaunchKernelGGL(mfma_gemm, dim3(16, 32, 1), b256, 0, stream,
        xab, wf1, (void*)hbuf, b1 + i * FQ, mask,
        MT, FQ, CQ, CQ, CQ, 0LL, 0LL, 1.f, 1 | 2 | 4 | 16);
    // FFN2 split-K=2 raw partials (256 blocks, Kh=1024)
    hipLaunchKernelGGL(mfma_gemm, dim3(4, 32, 2), b256, 0, stream,
        hbuf, wf2, (void*)t1, (const float*)0, mask,
        MT, CQ, FQ / 2, FQ, FQ, (long long)(FQ / 2), sY, 1.f, 32);
    hipLaunchKernelGGL(ln_rows, gln, b256, 0, stream,
        xa, t1, t1b, b2 + i * CQ, g2 + i * CQ, be2 + i * CQ, mask,
        xa, xab, 3);
  }
  hipLaunchKernelGGL(tr_out, gtr, dim3(32, 8), 0, stream, xa, out);
}